// Round 9
// baseline (109.660 us; speedup 1.0000x reference)
//
#include <hip/hip_runtime.h>

#define ROWS_PER_BLOCK 4
#define REPEAT 4  // diagnostic: replicate work to expose kernel in rocprof top-5

// GF(256) log/antilog tables (AES poly 0x11B, generator 3), built at compile time.
struct GFTables {
    unsigned char exp_[256];  // exp_[k] = 3^k for k in 0..254; exp_[255] dummy
    unsigned char log_[256];  // log_[v] for v in 1..255; log_[0] unused
    constexpr GFTables() : exp_(), log_() {
        int v = 1;
        for (int k = 0; k < 255; ++k) {
            exp_[k] = (unsigned char)v;
            log_[v] = (unsigned char)k;
            int x2 = (v << 1) ^ ((v & 0x80) ? 0x11B : 0);  // v*2
            v = (x2 ^ v) & 0xFF;                           // v*3
        }
        exp_[255] = 1;  // never used for a real write (guarded)
        log_[0] = 0;
    }
};
__constant__ GFTables gft{};

__device__ __forceinline__ float wave_max(float v) {
#pragma unroll
    for (int off = 32; off; off >>= 1) v = fmaxf(v, __shfl_xor(v, off));
    return v;
}
__device__ __forceinline__ float wave_sum(float v) {
#pragma unroll
    for (int off = 32; off; off >>= 1) v += __shfl_xor(v, off);
    return v;
}

// Wave-uniform broadcast of lane u's float, via v_readlane (scalar path, not DS pipe).
__device__ __forceinline__ float bcast(float v, int u) {
    return __int_as_float(__builtin_amdgcn_readlane(__float_as_int(v), u));
}

// One wave (64 lanes) per row. Each lane: 4 consecutive byte values on load,
// 4 consecutive dlog-domain outputs in the convolution.
extern "C" __global__ void __launch_bounds__(256, 4)
softgf256_kernel(const float* __restrict__ X, const float* __restrict__ Y,
                 float* __restrict__ OUT, int B) {
    __shared__ __align__(16) float s_pxp[ROWS_PER_BLOCK][256];  // px in dlog order, [255]=0 pad
    __shared__ __align__(16) float s_py2[ROWS_PER_BLOCK][512];  // py in dlog order, duplicated (mod-free)
    __shared__ __align__(16) float s_pz [ROWS_PER_BLOCK][256];  // log pz in byte order

    const int wave = threadIdx.x >> 6;
    const int lane = threadIdx.x & 63;
    // Diagnostic replication: blocks beyond B/ROWS_PER_BLOCK redo earlier rows,
    // writing byte-identical values (race-safe). Measures kernel time as
    // (dur - baseline)/(REPEAT-1) and lifts the kernel into rocprof's top-5.
    const int row = (blockIdx.x * ROWS_PER_BLOCK + wave) % B;

    const float* xr = X + (size_t)row * 256;
    const float* yr = Y + (size_t)row * 256;
    const int m0 = lane << 2;

    // ---- softmax (probability space) ----
    float4 x4 = *(const float4*)(xr + m0);
    float4 y4 = *(const float4*)(yr + m0);

    float mx = wave_max(fmaxf(fmaxf(x4.x, x4.y), fmaxf(x4.z, x4.w)));
    float my = wave_max(fmaxf(fmaxf(y4.x, y4.y), fmaxf(y4.z, y4.w)));

    float ex0 = __expf(x4.x - mx), ex1 = __expf(x4.y - mx);
    float ex2 = __expf(x4.z - mx), ex3 = __expf(x4.w - mx);
    float ey0 = __expf(y4.x - my), ey1 = __expf(y4.y - my);
    float ey2 = __expf(y4.z - my), ey3 = __expf(y4.w - my);

    float rxs = 1.0f / wave_sum(ex0 + ex1 + ex2 + ex3);
    float rys = 1.0f / wave_sum(ey0 + ey1 + ey2 + ey3);

    float* pxp = s_pxp[wave];
    float* py2 = s_py2[wave];
    float* pz  = s_pz[wave];

    float pxv[4] = {ex0 * rxs, ex1 * rxs, ex2 * rxs, ex3 * rxs};
    float pyv[4] = {ey0 * rys, ey1 * rys, ey2 * rys, ey3 * rys};

    float px0 = 0.0f, py0 = 0.0f;
#pragma unroll
    for (int q = 0; q < 4; ++q) {
        int v = m0 + q;
        if (v == 0) {  // lane 0 only
            px0 = pxv[q]; py0 = pyv[q];
            pxp[255] = 0.0f;  // pad so the conv loop can run a full 256 steps
        } else {
            int p = gft.log_[v];
            pxp[p] = pxv[q];
            py2[p] = pyv[q];
            py2[p + 255] = pyv[q];
            if (p < 2) py2[p + 510] = pyv[q];  // fill indices 510, 511
        }
    }
    // No barrier needed: each wave reads only LDS it wrote itself (in-order DS
    // pipe within a wave; compiler inserts the lgkmcnt waits).

    // Pull this lane's slice of px (dlog order) into registers ONCE; conv loop
    // broadcasts via v_readlane (halves DS-pipe instructions — round-8 change,
    // measured neutral, kept for structure).
    float4 pxq = *(const float4*)&pxp[m0];  // pxp[4*lane .. 4*lane+3], [255]=0 pad

    // ---- cyclic convolution, dlog domain ----
    // conv[m] = sum_s pxp[s] * py2[m - s + 255], outputs m = m0 .. m0+3 per lane.
    // NOTE: unroll capped at 4. Full unroll (64 iters) -> ~2.5 KB/thread scratch
    // spill -> 1.2 GB HBM traffic, 435 us (measured round 1).
    float acc0 = 0.f, acc1 = 0.f, acc2 = 0.f, acc3 = 0.f;
    float4 H = *(const float4*)&py2[m0 + 256];  // high half of sliding window
#pragma unroll 4
    for (int i = 0; i < 64; ++i) {
        float4 L = *(const float4*)&py2[m0 + 252 - (i << 2)];  // 16B-aligned, stride-1/lane
        // P = pxp[4i .. 4i+3], wave-uniform: readlane -> SGPR operand of v_fma.
        float pa = bcast(pxq.x, i);
        float pb = bcast(pxq.y, i);
        float pc = bcast(pxq.z, i);
        float pd = bcast(pxq.w, i);
        // step s = 4i+d uses window LH[q+3-d], LH = {L.x..L.w, H.x..H.w}
        acc0 = fmaf(pa, L.w, acc0);
        acc1 = fmaf(pa, H.x, acc1);
        acc2 = fmaf(pa, H.y, acc2);
        acc3 = fmaf(pa, H.z, acc3);
        acc0 = fmaf(pb, L.z, acc0);
        acc1 = fmaf(pb, L.w, acc1);
        acc2 = fmaf(pb, H.x, acc2);
        acc3 = fmaf(pb, H.y, acc3);
        acc0 = fmaf(pc, L.y, acc0);
        acc1 = fmaf(pc, L.z, acc1);
        acc2 = fmaf(pc, L.w, acc2);
        acc3 = fmaf(pc, H.x, acc3);
        acc0 = fmaf(pd, L.x, acc0);
        acc1 = fmaf(pd, L.y, acc1);
        acc2 = fmaf(pd, L.z, acc2);
        acc3 = fmaf(pd, L.w, acc3);
        H = L;
    }

    // ---- epilogue: log, permute back to byte order, coalesced store ----
    float l0 = __logf(acc0), l1 = __logf(acc1), l2 = __logf(acc2), l3 = __logf(acc3);
    pz[gft.exp_[m0 + 0]] = l0;
    pz[gft.exp_[m0 + 1]] = l1;
    pz[gft.exp_[m0 + 2]] = l2;
    if (lane != 63) pz[gft.exp_[m0 + 3]] = l3;  // m=255 is a duplicate of m=0, skip
    if (lane == 0) pz[0] = __logf(px0 + (1.0f - px0) * py0);

    *(float4*)(OUT + (size_t)row * 256 + m0) = *(const float4*)&pz[m0];
}

extern "C" void kernel_launch(void* const* d_in, const int* in_sizes, int n_in,
                              void* d_out, int out_size, void* d_ws, size_t ws_size,
                              hipStream_t stream) {
    const float* X = (const float*)d_in[0];
    const float* Y = (const float*)d_in[1];
    // d_in[2] (the int64 LUT) is intentionally unused: GF(256) tables are compile-time.
    float* OUT = (float*)d_out;
    const int B = in_sizes[0] / 256;
    const int blocks = REPEAT * ((B + ROWS_PER_BLOCK - 1) / ROWS_PER_BLOCK);
    hipLaunchKernelGGL(softgf256_kernel, dim3(blocks), dim3(256), 0, stream,
                       X, Y, OUT, B);
}

// Round 13
// 71.614 us; speedup vs baseline: 1.5313x; 1.5313x over previous
//
#include <hip/hip_runtime.h>

#define ROWS_PER_BLOCK 4

// GF(256) log/antilog tables (AES poly 0x11B, generator 3), built at compile time.
struct GFTables {
    unsigned char exp_[256];  // exp_[k] = 3^k for k in 0..254; exp_[255] dummy
    unsigned char log_[256];  // log_[v] for v in 1..255; log_[0] unused
    constexpr GFTables() : exp_(), log_() {
        int v = 1;
        for (int k = 0; k < 255; ++k) {
            exp_[k] = (unsigned char)v;
            log_[v] = (unsigned char)k;
            int x2 = (v << 1) ^ ((v & 0x80) ? 0x11B : 0);  // v*2
            v = (x2 ^ v) & 0xFF;                           // v*3
        }
        exp_[255] = 1;  // never used for a real write (guarded)
        log_[0] = 0;
    }
};
__constant__ GFTables gft{};

__device__ __forceinline__ float wave_max(float v) {
#pragma unroll
    for (int off = 32; off; off >>= 1) v = fmaxf(v, __shfl_xor(v, off));
    return v;
}
__device__ __forceinline__ float wave_sum(float v) {
#pragma unroll
    for (int off = 32; off; off >>= 1) v += __shfl_xor(v, off);
    return v;
}

// One wave (64 lanes) per row. Each lane: 4 consecutive byte values on load,
// 4 consecutive dlog-domain outputs in the convolution.
//
// Measured history (MI355X):
//  - full unroll: scratch spill -> 1.2 GB HBM traffic, 435 us   (round 1)
//  - unroll 4, LDS px broadcast: dur 72.2 us, kernel ~12 us     (round 7)
//  - readlane px broadcast: 74.5 us — readlane+mov burns VALU
//    slots while DS pipe has headroom; reverted                 (round 8)
//  - 4x-work probe: VALUBusy 80%, bank-conflicts negligible,
//    FETCH 4 MB (L3-resident) -> VALU-issue-bound               (round 9)
extern "C" __global__ void __launch_bounds__(256, 4)
softgf256_kernel(const float* __restrict__ X, const float* __restrict__ Y,
                 float* __restrict__ OUT, int B) {
    __shared__ __align__(16) float s_pxp[ROWS_PER_BLOCK][256];  // px in dlog order, [255]=0 pad
    __shared__ __align__(16) float s_py2[ROWS_PER_BLOCK][512];  // py in dlog order, duplicated (mod-free)
    __shared__ __align__(16) float s_pz [ROWS_PER_BLOCK][256];  // log pz in byte order

    const int wave = threadIdx.x >> 6;
    const int lane = threadIdx.x & 63;
    const int row  = blockIdx.x * ROWS_PER_BLOCK + wave;
    if (row >= B) return;

    const float* xr = X + (size_t)row * 256;
    const float* yr = Y + (size_t)row * 256;
    const int m0 = lane << 2;

    // ---- softmax (probability space) ----
    float4 x4 = *(const float4*)(xr + m0);
    float4 y4 = *(const float4*)(yr + m0);

    float mx = wave_max(fmaxf(fmaxf(x4.x, x4.y), fmaxf(x4.z, x4.w)));
    float my = wave_max(fmaxf(fmaxf(y4.x, y4.y), fmaxf(y4.z, y4.w)));

    float ex0 = __expf(x4.x - mx), ex1 = __expf(x4.y - mx);
    float ex2 = __expf(x4.z - mx), ex3 = __expf(x4.w - mx);
    float ey0 = __expf(y4.x - my), ey1 = __expf(y4.y - my);
    float ey2 = __expf(y4.z - my), ey3 = __expf(y4.w - my);

    float rxs = 1.0f / wave_sum(ex0 + ex1 + ex2 + ex3);
    float rys = 1.0f / wave_sum(ey0 + ey1 + ey2 + ey3);

    float* pxp = s_pxp[wave];
    float* py2 = s_py2[wave];
    float* pz  = s_pz[wave];

    float pxv[4] = {ex0 * rxs, ex1 * rxs, ex2 * rxs, ex3 * rxs};
    float pyv[4] = {ey0 * rys, ey1 * rys, ey2 * rys, ey3 * rys};

    float px0 = 0.0f, py0 = 0.0f;
#pragma unroll
    for (int q = 0; q < 4; ++q) {
        int v = m0 + q;
        if (v == 0) {  // lane 0 only
            px0 = pxv[q]; py0 = pyv[q];
            pxp[255] = 0.0f;  // pad so the conv loop can run a full 256 steps
        } else {
            int p = gft.log_[v];
            pxp[p] = pxv[q];
            py2[p] = pyv[q];
            py2[p + 255] = pyv[q];
            if (p < 2) py2[p + 510] = pyv[q];  // fill indices 510, 511
        }
    }
    // No barrier needed: each wave reads only LDS it wrote itself (in-order DS
    // pipe within a wave; compiler inserts the lgkmcnt waits).

    // ---- cyclic convolution, dlog domain ----
    // conv[m] = sum_s pxp[s] * py2[m - s + 255], outputs m = m0 .. m0+3 per lane.
    // px broadcast via uniform LDS b128 read (DS pipe has headroom; readlane
    // variant measured slower). Unroll 8: halves loop/addr overhead, VGPR stays
    // well under the launch_bounds cap of 128.
    float acc0 = 0.f, acc1 = 0.f, acc2 = 0.f, acc3 = 0.f;
    float4 H = *(const float4*)&py2[m0 + 256];  // high half of sliding window
#pragma unroll 8
    for (int sig = 0; sig <= 252; sig += 4) {
        float4 L = *(const float4*)&py2[m0 + 252 - sig];  // 16B-aligned, stride-1/lane
        float4 P = *(const float4*)&pxp[sig];             // uniform broadcast
        // step s = sig+d uses window LH[q+3-d], LH = {L.x..L.w, H.x..H.w}
        acc0 = fmaf(P.x, L.w, acc0);
        acc1 = fmaf(P.x, H.x, acc1);
        acc2 = fmaf(P.x, H.y, acc2);
        acc3 = fmaf(P.x, H.z, acc3);
        acc0 = fmaf(P.y, L.z, acc0);
        acc1 = fmaf(P.y, L.w, acc1);
        acc2 = fmaf(P.y, H.x, acc2);
        acc3 = fmaf(P.y, H.y, acc3);
        acc0 = fmaf(P.z, L.y, acc0);
        acc1 = fmaf(P.z, L.z, acc1);
        acc2 = fmaf(P.z, L.w, acc2);
        acc3 = fmaf(P.z, H.x, acc3);
        acc0 = fmaf(P.w, L.x, acc0);
        acc1 = fmaf(P.w, L.y, acc1);
        acc2 = fmaf(P.w, L.z, acc2);
        acc3 = fmaf(P.w, L.w, acc3);
        H = L;
    }

    // ---- epilogue: log, permute back to byte order, coalesced store ----
    float l0 = __logf(acc0), l1 = __logf(acc1), l2 = __logf(acc2), l3 = __logf(acc3);
    pz[gft.exp_[m0 + 0]] = l0;
    pz[gft.exp_[m0 + 1]] = l1;
    pz[gft.exp_[m0 + 2]] = l2;
    if (lane != 63) pz[gft.exp_[m0 + 3]] = l3;  // m=255 is a duplicate of m=0, skip
    if (lane == 0) pz[0] = __logf(px0 + (1.0f - px0) * py0);

    *(float4*)(OUT + (size_t)row * 256 + m0) = *(const float4*)&pz[m0];
}

extern "C" void kernel_launch(void* const* d_in, const int* in_sizes, int n_in,
                              void* d_out, int out_size, void* d_ws, size_t ws_size,
                              hipStream_t stream) {
    const float* X = (const float*)d_in[0];
    const float* Y = (const float*)d_in[1];
    // d_in[2] (the int64 LUT) is intentionally unused: GF(256) tables are compile-time.
    float* OUT = (float*)d_out;
    const int B = in_sizes[0] / 256;
    const int blocks = (B + ROWS_PER_BLOCK - 1) / ROWS_PER_BLOCK;
    hipLaunchKernelGGL(softgf256_kernel, dim3(blocks), dim3(256), 0, stream,
                       X, Y, OUT, B);
}